// Round 1
// 1093.131 us; speedup vs baseline: 10.0246x; 10.0246x over previous
//
#include <hip/hip_runtime.h>
#include <stdint.h>

typedef unsigned short u16;
typedef uint32_t u32;
typedef __attribute__((ext_vector_type(8))) short short8;
typedef __attribute__((ext_vector_type(4))) float f32x4;

__device__ __forceinline__ float bf2f(u16 v) {
  union { u32 u; float f; } c; c.u = ((u32)v) << 16; return c.f;
}
__device__ __forceinline__ u16 f2bf(float f) {
  union { float f; u32 u; } c; c.f = f;
  u32 r = c.u + 0x7fffu + ((c.u >> 16) & 1u);  // RNE
  return (u16)(r >> 16);
}
__device__ __forceinline__ void mode_store(void* p, size_t idx, float v, u32 fm) {
  if (fm) ((float*)p)[idx] = v;
  else    ((u16*)p)[idx]   = f2bf(v);
}

enum { EPI_PLANES = 0, EPI_EMB = 1, EPI_SCORES = 2, EPI_OUT = 3 };

// ---- dtype detection: low u16 of fp32 data is random mantissa bits -> wild bf16 ----
__global__ void detect_kernel(const u32* __restrict__ x, u32* __restrict__ flag) {
  __shared__ int cnt;
  if (threadIdx.x == 0) cnt = 0;
  __syncthreads();
  int wild = 0;
  #pragma unroll
  for (int c = 0; c < 4; ++c) {
    u32 u = x[threadIdx.x * 4 + c];
    float a = fabsf(bf2f((u16)(u & 0xffff)));
    if (!(a <= 1e6f) || (a != 0.f && a < 1e-20f)) wild++;  // !(a<=..) catches NaN
  }
  atomicAdd(&cnt, wild);
  __syncthreads();
  if (threadIdx.x == 0) flag[0] = (cnt > 100) ? 1u : 0u;  // 1 = fp32 inputs
}

// ---- canonicalize any input array to f32 (biases, centers) ----
__global__ void convert_kernel(const void* __restrict__ in, float* __restrict__ out,
                               int n, const u32* __restrict__ flag) {
  int i = blockIdx.x * 256 + threadIdx.x;
  if (i >= n) return;
  u32 fm = flag[0];
  out[i] = fm ? ((const float*)in)[i] : bf2f(((const u16*)in)[i]);
}

// ---- W[R=K][C=N] raw -> WT[N][K] in 3 bf16 planes (hi/mid/lo) ----
__global__ void trans_decomp_kernel(const void* __restrict__ in,
                                    u16* __restrict__ hi, u16* __restrict__ mid,
                                    u16* __restrict__ lo, int R, int C,
                                    const u32* __restrict__ flag) {
  __shared__ float t[32][33];
  u32 fm = flag[0];
  int x  = threadIdx.x & 31;
  int yq = threadIdx.x >> 5;
  int bx = blockIdx.x, by = blockIdx.y;
  #pragma unroll
  for (int yy = yq; yy < 32; yy += 8) {
    size_t src = (size_t)(by * 32 + yy) * C + bx * 32 + x;
    t[yy][x] = fm ? ((const float*)in)[src] : bf2f(((const u16*)in)[src]);
  }
  __syncthreads();
  #pragma unroll
  for (int yy = yq; yy < 32; yy += 8) {
    float v = t[x][yy];
    u16 h = f2bf(v);
    float r1 = v - bf2f(h);
    u16 m = f2bf(r1);
    u16 l = f2bf(r1 - bf2f(m));
    size_t dst = (size_t)(bx * 32 + yy) * R + by * 32 + x;
    hi[dst] = h; mid[dst] = m; lo[dst] = l;
  }
}

// ---- centers f32 -> 3 bf16 planes (same [K][D] layout, already B^T form) ----
__global__ void decomp_kernel(const float* __restrict__ in, u16* __restrict__ hi,
                              u16* __restrict__ mid, u16* __restrict__ lo, int n) {
  int i = blockIdx.x * 256 + threadIdx.x;
  if (i >= n) return;
  float v = in[i];
  u16 h = f2bf(v);
  float r1 = v - bf2f(h);
  u16 m = f2bf(r1);
  hi[i] = h; mid[i] = m; lo[i] = f2bf(r1 - bf2f(m));
}

// ---- c2[k] = sum_d centers[k][d]^2, from f32 centers, D=256 K=1024 ----
__global__ void c2_kernel(const float* __restrict__ cf, float* __restrict__ c2) {
  int w    = blockIdx.x * 4 + (threadIdx.x >> 6);
  int lane = threadIdx.x & 63;
  float4 v = *(const float4*)&cf[(size_t)w * 256 + lane * 4];
  float s = v.x * v.x + v.y * v.y + v.z * v.z + v.w * v.w;
  #pragma unroll
  for (int off = 32; off; off >>= 1) s += __shfl_down(s, off);
  if (lane == 0) c2[w] = s;
}

// ---- x chunk -> 3 bf16 planes (with element offset; dtype handled device-side) ----
__global__ void decomp_x_kernel(const void* __restrict__ in, u16* __restrict__ hi,
                                u16* __restrict__ mid, u16* __restrict__ lo,
                                int n, size_t eoff, const u32* __restrict__ flag) {
  int i = blockIdx.x * 256 + threadIdx.x;
  if (i >= n) return;
  u32 fm = flag[0];
  float v = fm ? ((const float*)in)[eoff + i] : bf2f(((const u16*)in)[eoff + i]);
  u16 h = f2bf(v);
  float r1 = v - bf2f(h);
  u16 m = f2bf(r1);
  hi[i] = h; mid[i] = m; lo[i] = f2bf(r1 - bf2f(m));
}

// ---- async stage of one 128x32 bf16 tile (8KB) into LDS via global_load_lds ----
// Tile rows are 64B contiguous in global ([*][K] layout, 32 bf16 per k-step).
// LDS layout: linear row*64B (+chunk*16B). Wave-uniform LDS base + lane*16 (HW rule).
__device__ __forceinline__ void stage_tile(const u16* __restrict__ g, u16* lbase,
                                           int Kst, int tid) {
  const int lane = tid & 63;
  const int wv   = tid >> 6;
  #pragma unroll
  for (int c = 0; c < 2; ++c) {
    const int li   = wv * 128 + c * 64 + lane;   // 16B-chunk index, 0..511
    const int row  = li >> 2;
    const int colb = (li & 3) * 16;
    const char* src = (const char*)g + (size_t)row * ((size_t)Kst * 2) + colb;
    u16* dst = lbase + (size_t)(wv * 128 + c * 64) * 8;  // wave-uniform
    __builtin_amdgcn_global_load_lds(
        (const __attribute__((address_space(1))) void*)src,
        (__attribute__((address_space(3))) void*)dst, 16, 0, 0);
  }
}

// Fully static GEMM body: C = act(sum_{pa+pw<=PCAP} Aplane[pa] @ Wplane[pw]^T + bias).
// A planes bf16 [M][K], W planes bf16 [N][K]. 128x128 tile, BK=32, 4 waves,
// 4x4 MFMA 16x16x32 per wave (m92/m97 layout). All plane counts COMPILE-TIME.
template<int nA, int nW, int PCAP, int RELU, int EPI, int NOUT>
__device__ __forceinline__ void gemm_body(
    const u16* __restrict__ A0, const u16* __restrict__ A1, const u16* __restrict__ A2,
    const u16* __restrict__ W0, const u16* __restrict__ W1, const u16* __restrict__ W2,
    const float* __restrict__ bias, const float* __restrict__ c2p,
    u16* __restrict__ O0, u16* __restrict__ O1, u16* __restrict__ O2,
    float* __restrict__ outf, void* __restrict__ dout, size_t doff,
    u32 fm, int M, int N, int K, u16* lds)
{
  const int tid  = threadIdx.x;
  const int lane = tid & 63;
  const int wid  = tid >> 6;
  const int m0 = blockIdx.y * 128;
  const int n0 = blockIdx.x * 128;
  const int wm = (wid & 1) * 64;
  const int wn = (wid >> 1) * 64;
  const u16* Ap[3] = {A0, A1, A2};
  const u16* Wp[3] = {W0, W1, W2};

  f32x4 acc[4][4];
  #pragma unroll
  for (int i = 0; i < 4; ++i)
    #pragma unroll
    for (int j = 0; j < 4; ++j)
      acc[i][j] = f32x4{0.f, 0.f, 0.f, 0.f};

  for (int k0 = 0; k0 < K; k0 += 32) {
    __syncthreads();
    #pragma unroll
    for (int p = 0; p < nA; ++p)
      stage_tile(Ap[p] + (size_t)m0 * K + k0, lds + p * 4096, K, tid);
    #pragma unroll
    for (int q = 0; q < nW; ++q)
      stage_tile(Wp[q] + (size_t)n0 * K + k0, lds + (nA + q) * 4096, K, tid);
    __syncthreads();  // compiler emits vmcnt(0) drain before barrier

    short8 bfrag[nW][4];
    #pragma unroll
    for (int q = 0; q < nW; ++q)
      #pragma unroll
      for (int j = 0; j < 4; ++j) {
        int r = wn + j * 16 + (lane & 15);
        bfrag[q][j] = *(const short8*)&lds[(nA + q) * 4096 + r * 32 + (lane >> 4) * 8];
      }
    #pragma unroll
    for (int pa = 0; pa < nA; ++pa) {
      short8 afrag[4];
      #pragma unroll
      for (int i = 0; i < 4; ++i) {
        int r = wm + i * 16 + (lane & 15);
        afrag[i] = *(const short8*)&lds[pa * 4096 + r * 32 + (lane >> 4) * 8];
      }
      #pragma unroll
      for (int pw = 0; pw < nW; ++pw) {
        if (pa + pw <= PCAP) {  // compile-time after unroll
          #pragma unroll
          for (int i = 0; i < 4; ++i)
            #pragma unroll
            for (int j = 0; j < 4; ++j)
              acc[i][j] = __builtin_amdgcn_mfma_f32_16x16x32_bf16(
                  afrag[i], bfrag[pw][j], acc[i][j], 0, 0, 0);
        }
      }
    }
  }

  // epilogue: C/D layout col=lane&15, row=(lane>>4)*4+reg
  #pragma unroll
  for (int i = 0; i < 4; ++i) {
    int rbase = m0 + wm + i * 16 + ((lane >> 4) * 4);
    #pragma unroll
    for (int j = 0; j < 4; ++j) {
      int col = n0 + wn + j * 16 + (lane & 15);
      float bv = 0.f, c2v = 0.f;
      if (EPI != EPI_SCORES) bv = bias[col];
      if (EPI == EPI_SCORES) c2v = c2p[col];
      #pragma unroll
      for (int r = 0; r < 4; ++r) {
        float v = acc[i][j][r] + bv;
        if (RELU) v = fmaxf(v, 0.f);
        size_t idx = (size_t)(rbase + r) * N + col;
        if (EPI == EPI_SCORES) {
          outf[idx] = c2v - 2.f * v;
        } else {
          if (NOUT >= 1) {
            u16 h = f2bf(v);
            O0[idx] = h;
            if (NOUT >= 2) {
              float r1 = v - bf2f(h);
              u16 m = f2bf(r1);
              O1[idx] = m;
              if (NOUT >= 3) O2[idx] = f2bf(r1 - bf2f(m));
            }
          }
          if (EPI == EPI_EMB || EPI == EPI_OUT) mode_store(dout, doff + idx, v, fm);
        }
      }
    }
  }
}

// Kernel wrapper: uniform branch on runtime dtype flag selects a fully-static body.
// fp32 mode: (NA, NW) planes; bf16 mode: (ARAW?1:NA) A-planes x 1 W-plane.
template<int NA, int NW, int PCAP, int RELU, int EPI, int NOUT, int ARAW>
__global__ __launch_bounds__(256)
void gemm_kernel(const u16* A0, const u16* A1, const u16* A2,
                 const u16* W0, const u16* W1, const u16* W2,
                 const float* __restrict__ bias, const float* __restrict__ c2p,
                 u16* O0, u16* O1, u16* O2,
                 float* outf, void* dout, size_t doff,
                 const u32* __restrict__ flag, int M, int N, int K)
{
  __shared__ __align__(16) u16 lds[(NA + NW) * 4096];
  const u32 fm = flag[0];
  if (fm)
    gemm_body<NA, NW, PCAP, RELU, EPI, NOUT>(A0, A1, A2, W0, W1, W2, bias, c2p,
                                             O0, O1, O2, outf, dout, doff, fm, M, N, K, lds);
  else
    gemm_body<(ARAW ? 1 : NA), 1, PCAP, RELU, EPI, NOUT>(A0, A1, A2, W0, W1, W2, bias, c2p,
                                             O0, O1, O2, outf, dout, doff, fm, M, N, K, lds);
}

// per-row argmin over K=1024 (np first-index tie-break) -> one-hot at d_out element offset
__global__ void argmin_onehot(const float* __restrict__ scores, void* __restrict__ dout,
                              size_t doff, const u32* __restrict__ flag) {
  const int Kc = 1024;
  u32 fm  = flag[0];
  int row  = blockIdx.x * 4 + (threadIdx.x >> 6);
  int lane = threadIdx.x & 63;
  const float* s = scores + (size_t)row * Kc;
  float bestv = 3.4e38f;
  int   besti = Kc;
  #pragma unroll
  for (int base = 0; base < Kc; base += 256) {
    float4 v = *(const float4*)&s[base + lane * 4];
    int i0 = base + lane * 4;
    if (v.x < bestv) { bestv = v.x; besti = i0; }
    if (v.y < bestv) { bestv = v.y; besti = i0 + 1; }
    if (v.z < bestv) { bestv = v.z; besti = i0 + 2; }
    if (v.w < bestv) { bestv = v.w; besti = i0 + 3; }
  }
  #pragma unroll
  for (int off = 32; off; off >>= 1) {
    float ov = __shfl_down(bestv, off);
    int   oi = __shfl_down(besti, off);
    if (ov < bestv || (ov == bestv && oi < besti)) { bestv = ov; besti = oi; }
  }
  besti = __shfl(besti, 0);
  size_t eb = doff + (size_t)row * Kc + lane * 16;
  if (fm) {
    float* op = (float*)dout;
    #pragma unroll
    for (int q = 0; q < 16; ++q)
      op[eb + q] = (lane * 16 + q == besti) ? 1.0f : 0.0f;
  } else {
    u16* op = (u16*)dout + eb;
    uint32_t w[8];
    #pragma unroll
    for (int q = 0; q < 8; ++q) {
      int c0 = lane * 16 + q * 2;
      w[q] = ((c0 == besti) ? 0x3F80u : 0u) | (((c0 + 1 == besti) ? 0x3F80u : 0u) << 16);
    }
    *(uint4*)op       = make_uint4(w[0], w[1], w[2], w[3]);
    *(uint4*)(op + 8) = make_uint4(w[4], w[5], w[6], w[7]);
  }
}

extern "C" void kernel_launch(void* const* d_in, const int* in_sizes, int n_in,
                              void* d_out, int out_size, void* d_ws, size_t ws_size,
                              hipStream_t stream) {
  const int Bn = 8192;
  const int ENC[5] = {1024, 2048, 1024, 512, 256};
  const int DEC[5] = {256, 512, 1024, 2048, 1024};

  const void* x = d_in[0];
  const void *We[4], *be[4], *Wd[4], *bd[4];
  for (int i = 0; i < 4; ++i) { We[i] = d_in[1 + 2 * i]; be[i] = d_in[2 + 2 * i]; }
  for (int i = 0; i < 4; ++i) { Wd[i] = d_in[9 + 2 * i]; bd[i] = d_in[10 + 2 * i]; }
  const void* centers = d_in[17];

  // ---- fixed workspace carve ----
  char* wsb = (char*)d_ws;
  size_t o = 0;
  auto carve = [&](size_t bytes) { void* p = wsb + o; o += (bytes + 63) & ~size_t(63); return p; };
  u32* flag = (u32*)carve(64);
  u16 *WTe[4][3], *WTd[4][3];
  for (int i = 0; i < 4; ++i)
    for (int p = 0; p < 3; ++p) WTe[i][p] = (u16*)carve((size_t)ENC[i] * ENC[i + 1] * 2);
  for (int i = 0; i < 4; ++i)
    for (int p = 0; p < 3; ++p) WTd[i][p] = (u16*)carve((size_t)DEC[i] * DEC[i + 1] * 2);
  float* bef[4]; float* bdf[4];
  for (int i = 0; i < 4; ++i) bef[i] = (float*)carve((size_t)ENC[i + 1] * 4);
  for (int i = 0; i < 4; ++i) bdf[i] = (float*)carve((size_t)DEC[i + 1] * 4);
  float* cenf = (float*)carve(1024 * 256 * 4);
  u16* cen[3];
  for (int p = 0; p < 3; ++p) cen[p] = (u16*)carve(1024 * 256 * 2);
  float* c2 = (float*)carve(1024 * 4);

  // ---- chunk size from remaining ws; per-chunk activation planes: 29184 B/row ----
  size_t rem = (ws_size > o) ? ws_size - o - 4096 : 0;
  int CH = 256;
  for (int c = 8192; c >= 256; c >>= 1)
    if ((size_t)c * 29184 <= rem) { CH = c; break; }
  const int nch = Bn / CH;

  u16* xp[3];  for (int p = 0; p < 3; ++p) xp[p]  = (u16*)carve((size_t)CH * 1024 * 2);
  u16* h1p[3]; for (int p = 0; p < 3; ++p) h1p[p] = (u16*)carve((size_t)CH * 2048 * 2);
  u16* h2p[3]; for (int p = 0; p < 3; ++p) h2p[p] = (u16*)carve((size_t)CH * 1024 * 2);
  u16* h3p[3]; for (int p = 0; p < 3; ++p) h3p[p] = (u16*)carve((size_t)CH * 512 * 2);
  u16* ep[3];  for (int p = 0; p < 3; ++p) ep[p]  = (u16*)carve((size_t)CH * 256 * 2);
  // overlays (stream-ordered reuse of dead regions):
  float* scores = (float*)xp[0];            // CH*4096 B <= xp region CH*6144; xp dead after L0
  char* dreg = (char*)h1p[0];               // h1p+h2p region: CH*18432 B, dead after L1/L2
  u16* g1p[2] = {(u16*)dreg,                        (u16*)(dreg + (size_t)CH * 1024)};
  u16* g2p[2] = {(u16*)(dreg + (size_t)CH * 2048),  (u16*)(dreg + (size_t)CH * 4096)};
  u16* g3p[2] = {(u16*)(dreg + (size_t)CH * 6144),  (u16*)(dreg + (size_t)CH * 10240)};

  const size_t off_emb    = (size_t)Bn * 1024;
  const size_t off_labels = (size_t)Bn * 1280;

  // ---- prep: detect dtype, convert/transpose/decompose params ----
  detect_kernel<<<1, 256, 0, stream>>>((const u32*)x, flag);
  for (int i = 0; i < 4; ++i)
    trans_decomp_kernel<<<dim3(ENC[i + 1] / 32, ENC[i] / 32), 256, 0, stream>>>(
        We[i], WTe[i][0], WTe[i][1], WTe[i][2], ENC[i], ENC[i + 1], flag);
  for (int i = 0; i < 4; ++i)
    trans_decomp_kernel<<<dim3(DEC[i + 1] / 32, DEC[i] / 32), 256, 0, stream>>>(
        Wd[i], WTd[i][0], WTd[i][1], WTd[i][2], DEC[i], DEC[i + 1], flag);
  for (int i = 0; i < 4; ++i) {
    convert_kernel<<<(ENC[i + 1] + 255) / 256, 256, 0, stream>>>(be[i], bef[i], ENC[i + 1], flag);
    convert_kernel<<<(DEC[i + 1] + 255) / 256, 256, 0, stream>>>(bd[i], bdf[i], DEC[i + 1], flag);
  }
  convert_kernel<<<(1024 * 256) / 256, 256, 0, stream>>>(centers, cenf, 1024 * 256, flag);
  decomp_kernel<<<(1024 * 256) / 256, 256, 0, stream>>>(cenf, cen[0], cen[1], cen[2], 1024 * 256);
  c2_kernel<<<256, 256, 0, stream>>>(cenf, c2);

  const int GY = CH / 128;
  for (int c = 0; c < nch; ++c) {
    decomp_x_kernel<<<(CH * 1024) / 256, 256, 0, stream>>>(
        x, xp[0], xp[1], xp[2], CH * 1024, (size_t)c * CH * 1024, flag);

    // encoder
    gemm_kernel<3, 3, 2, 1, EPI_PLANES, 3, 1><<<dim3(16, GY), 256, 0, stream>>>(
        xp[0], xp[1], xp[2], WTe[0][0], WTe[0][1], WTe[0][2], bef[0], nullptr,
        h1p[0], h1p[1], h1p[2], nullptr, nullptr, 0, flag, CH, 2048, 1024);
    gemm_kernel<3, 3, 2, 1, EPI_PLANES, 3, 0><<<dim3(8, GY), 256, 0, stream>>>(
        h1p[0], h1p[1], h1p[2], WTe[1][0], WTe[1][1], WTe[1][2], bef[1], nullptr,
        h2p[0], h2p[1], h2p[2], nullptr, nullptr, 0, flag, CH, 1024, 2048);
    gemm_kernel<3, 3, 2, 1, EPI_PLANES, 3, 0><<<dim3(4, GY), 256, 0, stream>>>(
        h2p[0], h2p[1], h2p[2], WTe[2][0], WTe[2][1], WTe[2][2], bef[2], nullptr,
        h3p[0], h3p[1], h3p[2], nullptr, nullptr, 0, flag, CH, 512, 1024);
    gemm_kernel<3, 3, 2, 0, EPI_EMB, 3, 0><<<dim3(2, GY), 256, 0, stream>>>(
        h3p[0], h3p[1], h3p[2], WTe[3][0], WTe[3][1], WTe[3][2], bef[3], nullptr,
        ep[0], ep[1], ep[2], nullptr, d_out, off_emb + (size_t)c * CH * 256,
        flag, CH, 256, 512);

    // scores + labels
    gemm_kernel<3, 3, 2, 0, EPI_SCORES, 0, 0><<<dim3(8, GY), 256, 0, stream>>>(
        ep[0], ep[1], ep[2], cen[0], cen[1], cen[2], nullptr, c2,
        nullptr, nullptr, nullptr, scores, nullptr, 0, flag, CH, 1024, 256);
    argmin_onehot<<<CH / 4, 256, 0, stream>>>(scores, d_out,
        off_labels + (size_t)c * CH * 1024, flag);

    // decoder
    gemm_kernel<2, 2, 1, 1, EPI_PLANES, 2, 0><<<dim3(4, GY), 256, 0, stream>>>(
        ep[0], ep[1], nullptr, WTd[0][0], WTd[0][1], nullptr, bdf[0], nullptr,
        g1p[0], g1p[1], nullptr, nullptr, nullptr, 0, flag, CH, 512, 256);
    gemm_kernel<2, 2, 1, 1, EPI_PLANES, 2, 0><<<dim3(8, GY), 256, 0, stream>>>(
        g1p[0], g1p[1], nullptr, WTd[1][0], WTd[1][1], nullptr, bdf[1], nullptr,
        g2p[0], g2p[1], nullptr, nullptr, nullptr, 0, flag, CH, 1024, 512);
    gemm_kernel<2, 2, 1, 1, EPI_PLANES, 2, 0><<<dim3(16, GY), 256, 0, stream>>>(
        g2p[0], g2p[1], nullptr, WTd[2][0], WTd[2][1], nullptr, bdf[2], nullptr,
        g3p[0], g3p[1], nullptr, nullptr, nullptr, 0, flag, CH, 2048, 1024);
    gemm_kernel<2, 2, 1, 0, EPI_OUT, 0, 0><<<dim3(8, GY), 256, 0, stream>>>(
        g3p[0], g3p[1], nullptr, WTd[3][0], WTd[3][1], nullptr, bdf[3], nullptr,
        nullptr, nullptr, nullptr, nullptr, d_out, (size_t)c * CH * 1024,
        flag, CH, 1024, 2048);
  }

  (void)in_sizes; (void)n_in; (void)out_size;
}